// Round 2
// baseline (18845.540 us; speedup 1.0000x reference)
//
#include <hip/hip_runtime.h>
#include <cstdint>
#include <math.h>

#define B_ 512
#define S_ 100
#define E_ 256
#define H_ 256

__device__ __forceinline__ float sigmoidf_(float x){ return 1.0f/(1.0f+expf(-x)); }

// Threefry-2x32, 20 rounds — matches jax/_src/prng.py lowering exactly.
__device__ __forceinline__ void threefry2x32_(uint32_t k0, uint32_t k1,
                                              uint32_t c0, uint32_t c1,
                                              uint32_t& o0, uint32_t& o1){
  uint32_t ks2 = k0 ^ k1 ^ 0x1BD11BDAu;
  uint32_t x0 = c0 + k0, x1 = c1 + k1;
#define ROT_(x,d) (((x)<<(d))|((x)>>(32-(d))))
#define RND_(r) { x0 += x1; x1 = ROT_(x1,(r)); x1 ^= x0; }
  RND_(13) RND_(15) RND_(26) RND_(6)  x0 += k1;  x1 += ks2 + 1u;
  RND_(17) RND_(29) RND_(16) RND_(24) x0 += ks2; x1 += k0  + 2u;
  RND_(13) RND_(15) RND_(26) RND_(6)  x0 += k0;  x1 += k1  + 3u;
  RND_(17) RND_(29) RND_(16) RND_(24) x0 += k1;  x1 += ks2 + 4u;
  RND_(13) RND_(15) RND_(26) RND_(6)  x0 += ks2; x1 += k0  + 5u;
#undef RND_
#undef ROT_
  o0 = x0; o1 = x1;
}

// jax.random.uniform(minval=tiny,maxval=1) + gumbel transform, f32-exact.
__device__ __forceinline__ float gumbel_bits_(uint32_t bits){
  const float tiny = 1.175494350822287508e-38f;
  float u = __uint_as_float((bits >> 9) | 0x3f800000u) - 1.0f; // [0,1)
  u = fmaxf(tiny, u + tiny);  // u*(1-tiny)+tiny : (1-tiny)==1.0f in f32
  return -logf(-logf(u));
}

__device__ __forceinline__ float wsum_(float v){
  #pragma unroll
  for (int d = 32; d > 0; d >>= 1) v += __shfl_xor(v, d, 64);
  return v;
}
__device__ __forceinline__ float wmax_(float v){
  #pragma unroll
  for (int d = 32; d > 0; d >>= 1) v = fmaxf(v, __shfl_xor(v, d, 64));
  return v;
}

// ---------- prep kernels ----------
// Wt[k][j] = k<256 ? Wih[j][k] : Whh[j][k-256]   (k-major for coalesced reads)
__global__ __launch_bounds__(256) void prep_wt(const float* __restrict__ Wih,
                                               const float* __restrict__ Whh,
                                               float* __restrict__ Wt){
  int idx = blockIdx.x*256 + threadIdx.x;            // 512*1024
  int k = idx >> 10, j = idx & 1023;
  Wt[idx] = (k < 256) ? Wih[j*256 + k] : Whh[j*256 + (k-256)];
}
__global__ __launch_bounds__(256) void prep_bias(const float* __restrict__ b1,
                                                 const float* __restrict__ b2,
                                                 float* __restrict__ o, int n){
  int i = blockIdx.x*256 + threadIdx.x; if (i < n) o[i] = b1[i] + b2[i];
}
// dst[k][u] = src[u][k]  (256x256)
__global__ __launch_bounds__(256) void transpose256(const float* __restrict__ src,
                                                    float* __restrict__ dst){
  int idx = blockIdx.x*256 + threadIdx.x;            // 65536
  int r = idx >> 8, cc = idx & 255;
  dst[idx] = src[cc*256 + r];
}
__global__ __launch_bounds__(256) void init_state(float* __restrict__ h, float* __restrict__ c,
                                                  int* __restrict__ mask, int* __restrict__ sel){
  int i = blockIdx.x*256 + threadIdx.x;              // 512 blocks
  if (i < B_*H_) { h[i] = 0.f; c[i] = 0.f; }
  if (i < B_*S_) mask[i] = 0;
  if (i < B_)    sel[i]  = -1;
}

// ---------- fused LSTM step (gates GEMM + cell pointwise) ----------
// block: 256 thr, 4 batch rows. thread tid owns hidden unit u=tid, all 4 gates.
__global__ __launch_bounds__(256) void lstm_step_kernel(
    const float* __restrict__ Wt,     // [512][1024] k-major
    const float* __restrict__ bsum,   // [1024] bih+bhh
    const float* __restrict__ coords, // inputs [B,2,S]
    const float* __restrict__ emb,    // [2,256]
    const float* __restrict__ start,  // [256] (decoder) or null
    const int*   __restrict__ sel,    // [B] (decoder) or null
    float* __restrict__ h, float* __restrict__ c,
    float* __restrict__ enc_out,      // [B,S,H] (encoder) or null
    int t, int mode)
{
  const int tid = threadIdx.x;
  const int b0  = blockIdx.x * 4;
  __shared__ float xh[4][512];

  const float e0 = emb[tid], e1 = emb[256 + tid];
  #pragma unroll
  for (int r = 0; r < 4; ++r) {
    const int b = b0 + r;
    float xv;
    if (mode == 0) {
      xv = coords[b*200 + t]*e0 + coords[b*200 + 100 + t]*e1;
    } else {
      int s = sel[b];
      if (s < 0) xv = start[tid];
      else       xv = coords[b*200 + s]*e0 + coords[b*200 + 100 + s]*e1;
    }
    xh[r][tid]       = xv;
    xh[r][256 + tid] = h[b*256 + tid];
  }
  __syncthreads();

  float acc[4][4] = {};
  #pragma unroll 4
  for (int k = 0; k < 512; ++k) {
    const float* wr = Wt + (size_t)k*1024 + tid;
    const float w0 = wr[0], w1 = wr[256], w2 = wr[512], w3 = wr[768];
    #pragma unroll
    for (int r = 0; r < 4; ++r) {
      const float xv = xh[r][k];
      acc[r][0] += xv*w0; acc[r][1] += xv*w1;
      acc[r][2] += xv*w2; acc[r][3] += xv*w3;
    }
  }

  const float bi_ = bsum[tid], bf_ = bsum[256+tid], bg_ = bsum[512+tid], bo_ = bsum[768+tid];
  #pragma unroll
  for (int r = 0; r < 4; ++r) {
    const int b = b0 + r;
    const float gi = acc[r][0] + bi_;
    const float gf = acc[r][1] + bf_;
    const float gg = acc[r][2] + bg_;
    const float go = acc[r][3] + bo_;
    const float cN = sigmoidf_(gf)*c[b*256+tid] + sigmoidf_(gi)*tanhf(gg);
    const float hN = sigmoidf_(go)*tanhf(cN);
    c[b*256 + tid] = cN;
    h[b*256 + tid] = hN;
    if (mode == 0) enc_out[((size_t)b*S_ + t)*H_ + tid] = hN;
  }
}

// ---------- ref_g / ref_p projection GEMM: C[M,256] = A[M,256]@Bt[256,256] + bias ----------
__global__ __launch_bounds__(256) void gemm_ref(
    const float* __restrict__ A, const float* __restrict__ Bt,
    const float* __restrict__ bias, float* __restrict__ C)
{
  const int tid = threadIdx.x;
  const int m0 = blockIdx.x * 128, n0 = blockIdx.y * 128;
  __shared__ float As[8][128];
  __shared__ float Bs[8][128];
  float acc[8][8] = {};
  const int tx = tid & 15, ty = tid >> 4;

  for (int k0 = 0; k0 < 256; k0 += 8) {
    {
      const int row = tid >> 1, q = tid & 1;
      const float4 av = *(const float4*)(A + (size_t)(m0+row)*256 + k0 + q*4);
      As[q*4+0][row] = av.x; As[q*4+1][row] = av.y;
      As[q*4+2][row] = av.z; As[q*4+3][row] = av.w;
    }
    {
      const int kk = tid >> 5, nq = tid & 31;
      *(float4*)(&Bs[kk][nq*4]) = *(const float4*)(Bt + (size_t)(k0+kk)*256 + n0 + nq*4);
    }
    __syncthreads();
    #pragma unroll
    for (int k = 0; k < 8; ++k) {
      float a[8], bb[8];
      *(float4*)&a[0]  = *(const float4*)&As[k][ty*8];
      *(float4*)&a[4]  = *(const float4*)&As[k][ty*8+4];
      *(float4*)&bb[0] = *(const float4*)&Bs[k][tx*8];
      *(float4*)&bb[4] = *(const float4*)&Bs[k][tx*8+4];
      #pragma unroll
      for (int i = 0; i < 8; ++i)
        #pragma unroll
        for (int j = 0; j < 8; ++j)
          acc[i][j] += a[i]*bb[j];
    }
    __syncthreads();
  }
  #pragma unroll
  for (int i = 0; i < 8; ++i) {
    const int m = m0 + ty*8 + i;
    #pragma unroll
    for (int j = 0; j < 8; j += 4) {
      const int n = n0 + tx*8 + j;
      float4 o;
      o.x = acc[i][j  ] + bias[n  ];
      o.y = acc[i][j+1] + bias[n+1];
      o.z = acc[i][j+2] + bias[n+2];
      o.w = acc[i][j+3] + bias[n+3];
      *(float4*)(C + (size_t)m*256 + n) = o;
    }
  }
}

// ---------- decoder attention + softmax + categorical sampling, one block per b ----------
__global__ __launch_bounds__(256) void attn_step(
    const float* __restrict__ h, const float* __restrict__ enc,
    const float* __restrict__ ref_g, const float* __restrict__ ref_p,
    const float* __restrict__ gWqT, const float* __restrict__ g_bq, const float* __restrict__ g_V,
    const float* __restrict__ pWqT, const float* __restrict__ p_bq, const float* __restrict__ p_V,
    int* __restrict__ mask, int* __restrict__ sel,
    float* __restrict__ probs_out, float* __restrict__ idx_out, int t)
{
  const int b    = blockIdx.x;
  const int tid  = threadIdx.x;
  const int lane = tid & 63;
  const int wv   = tid >> 6;

  __shared__ float hs[256], qqs[256], qs[256], pqs[256];
  __shared__ float gVs[256], pVs[256];
  __shared__ float lg[128], alpha[128], lp[128];

  hs[tid]  = h[b*256 + tid];
  gVs[tid] = g_V[tid];
  pVs[tid] = p_V[tid];
  __syncthreads();

  { // qq = g_bq + h @ g_Wq^T
    float a = g_bq[tid];
    for (int k = 0; k < 256; ++k) a += hs[k] * gWqT[k*256 + tid];
    qqs[tid] = a;
  }
  __syncthreads();

  { // glimpse logits, masked
    const float* rg = ref_g + (size_t)b*S_*H_;
    const int* mk = mask + b*S_;
    for (int is = 0; is < 25; ++is) {
      const int s = is*4 + wv;
      float p = 0.f;
      #pragma unroll
      for (int j = 0; j < 4; ++j) {
        const int hh = lane + 64*j;
        p += gVs[hh] * tanhf(qqs[hh] + rg[s*256 + hh]);
      }
      p = wsum_(p);
      if (lane == 0) lg[s] = mk[s] ? -INFINITY : p;
    }
  }
  __syncthreads();

  if (wv == 0) { // softmax(lg) -> alpha
    const float v0 = lg[lane];
    const float v1 = (lane + 64 < S_) ? lg[lane + 64] : -INFINITY;
    const float m  = wmax_(fmaxf(v0, v1));
    const float e0 = expf(v0 - m);
    const float e1 = (lane + 64 < S_) ? expf(v1 - m) : 0.f;
    const float sm = wsum_(e0 + e1);
    alpha[lane] = e0 / sm;
    if (lane + 64 < S_) alpha[lane + 64] = e1 / sm;
  }
  __syncthreads();

  { // q = sum_s alpha[s] * enc[b,s,:]
    const float* eb = enc + (size_t)b*S_*H_;
    float a = 0.f;
    for (int s = 0; s < S_; ++s) a += alpha[s] * eb[s*256 + tid];
    qs[tid] = a;
  }
  __syncthreads();

  { // pq = p_bq + q @ p_Wq^T
    float a = p_bq[tid];
    for (int k = 0; k < 256; ++k) a += qs[k] * pWqT[k*256 + tid];
    pqs[tid] = a;
  }
  __syncthreads();

  { // pointer logits: 10*tanh(attn), then mask
    const float* rp = ref_p + (size_t)b*S_*H_;
    const int* mk = mask + b*S_;
    for (int is = 0; is < 25; ++is) {
      const int s = is*4 + wv;
      float p = 0.f;
      #pragma unroll
      for (int j = 0; j < 4; ++j) {
        const int hh = lane + 64*j;
        p += pVs[hh] * tanhf(pqs[hh] + rp[s*256 + hh]);
      }
      p = wsum_(p);
      if (lane == 0) {
        const float v = 10.0f * tanhf(p);
        lp[s] = mk[s] ? -INFINITY : v;
      }
    }
  }
  __syncthreads();

  if (wv == 0) { // probs + gumbel-argmax sampling (threefry partitionable)
    const float v0 = lp[lane];
    const float v1 = (lane + 64 < S_) ? lp[lane + 64] : -INFINITY;
    const float m  = wmax_(fmaxf(v0, v1));
    const float e0 = expf(v0 - m);
    const float e1 = (lane + 64 < S_) ? expf(v1 - m) : 0.f;
    const float sm = wsum_(e0 + e1);
    float* po = probs_out + ((size_t)t*B_ + b)*S_;
    po[lane] = e0 / sm;
    if (lane + 64 < S_) po[lane + 64] = e1 / sm;

    // step key: keys[t] = threefry((0,1),(0,t))  [foldlike split]
    uint32_t k0, k1; threefry2x32_(0u, 1u, 0u, (uint32_t)t, k0, k1);
    // partitionable random_bits(32): bits = o0 ^ o1 of block with counter (0, flat_idx)
    uint32_t r0, r1;
    threefry2x32_(k0, k1, 0u, (uint32_t)(b*S_ + lane), r0, r1);
    float z0 = v0 + gumbel_bits_(r0 ^ r1);
    float z1 = -INFINITY;
    if (lane + 64 < S_) {
      uint32_t q0, q1;
      threefry2x32_(k0, k1, 0u, (uint32_t)(b*S_ + lane + 64), q0, q1);
      z1 = v1 + gumbel_bits_(q0 ^ q1);
    }
    float bv; int bi;
    if (z1 > z0) { bv = z1; bi = lane + 64; } else { bv = z0; bi = lane; }
    #pragma unroll
    for (int d = 32; d > 0; d >>= 1) {
      const float ov = __shfl_xor(bv, d, 64);
      const int   oi = __shfl_xor(bi, d, 64);
      if (ov > bv || (ov == bv && oi < bi)) { bv = ov; bi = oi; }
    }
    if (lane == 0) {
      idx_out[t*B_ + b] = (float)bi;
      sel[b] = bi;
      mask[b*S_ + bi] = 1;
    }
  }
}

extern "C" void kernel_launch(void* const* d_in, const int* in_sizes, int n_in,
                              void* d_out, int out_size, void* d_ws, size_t ws_size,
                              hipStream_t stream) {
  (void)in_sizes; (void)n_in; (void)out_size; (void)ws_size;
  const float* inputs = (const float*)d_in[0];
  const float* emb    = (const float*)d_in[1];
  const float* eWih   = (const float*)d_in[2];
  const float* eWhh   = (const float*)d_in[3];
  const float* ebih   = (const float*)d_in[4];
  const float* ebhh   = (const float*)d_in[5];
  const float* dWih   = (const float*)d_in[6];
  const float* dWhh   = (const float*)d_in[7];
  const float* dbih   = (const float*)d_in[8];
  const float* dbhh   = (const float*)d_in[9];
  const float* gWq    = (const float*)d_in[10];
  const float* gbq    = (const float*)d_in[11];
  const float* gWr    = (const float*)d_in[12];
  const float* gbr    = (const float*)d_in[13];
  const float* gV     = (const float*)d_in[14];
  const float* pWq    = (const float*)d_in[15];
  const float* pbq    = (const float*)d_in[16];
  const float* pWr    = (const float*)d_in[17];
  const float* pbr    = (const float*)d_in[18];
  const float* pV     = (const float*)d_in[19];
  const float* start  = (const float*)d_in[20];

  float* ws = (float*)d_ws;
  size_t o = 0;
  float* WtE  = ws + o; o += (size_t)512*1024;
  float* WtD  = ws + o; o += (size_t)512*1024;
  float* bE   = ws + o; o += 1024;
  float* bD   = ws + o; o += 1024;
  float* gWqT = ws + o; o += 65536;
  float* pWqT = ws + o; o += 65536;
  float* gWrT = ws + o; o += 65536;
  float* pWrT = ws + o; o += 65536;
  float* enc  = ws + o; o += (size_t)B_*S_*H_;
  float* refg = ws + o; o += (size_t)B_*S_*H_;
  float* refp = ws + o; o += (size_t)B_*S_*H_;
  float* h    = ws + o; o += (size_t)B_*H_;
  float* c    = ws + o; o += (size_t)B_*H_;
  int* mask   = (int*)(ws + o); o += (size_t)B_*S_;
  int* sel    = (int*)(ws + o); o += B_;

  float* probs = (float*)d_out;
  float* idxo  = probs + (size_t)S_*B_*S_;

  prep_wt<<<2048,256,0,stream>>>(eWih, eWhh, WtE);
  prep_wt<<<2048,256,0,stream>>>(dWih, dWhh, WtD);
  prep_bias<<<4,256,0,stream>>>(ebih, ebhh, bE, 1024);
  prep_bias<<<4,256,0,stream>>>(dbih, dbhh, bD, 1024);
  transpose256<<<256,256,0,stream>>>(gWq, gWqT);
  transpose256<<<256,256,0,stream>>>(pWq, pWqT);
  transpose256<<<256,256,0,stream>>>(gWr, gWrT);
  transpose256<<<256,256,0,stream>>>(pWr, pWrT);
  init_state<<<512,256,0,stream>>>(h, c, mask, sel);

  for (int t = 0; t < S_; ++t)
    lstm_step_kernel<<<128,256,0,stream>>>(WtE, bE, inputs, emb, nullptr, nullptr,
                                           h, c, enc, t, 0);

  gemm_ref<<<dim3(400,2),256,0,stream>>>(enc, gWrT, gbr, refg);
  gemm_ref<<<dim3(400,2),256,0,stream>>>(enc, pWrT, pbr, refp);

  for (int t = 0; t < S_; ++t) {
    lstm_step_kernel<<<128,256,0,stream>>>(WtD, bD, inputs, emb, start, sel,
                                           h, c, nullptr, t, 1);
    attn_step<<<512,256,0,stream>>>(h, enc, refg, refp,
                                    gWqT, gbq, gV, pWqT, pbq, pV,
                                    mask, sel, probs, idxo, t);
  }
}